// Round 1
// baseline (3063.241 us; speedup 1.0000x reference)
//
#include <hip/hip_runtime.h>

// ---------------------------------------------------------------------------
// Round-6: fuse ALL 48 biLSTM layers into ONE kernel.
//
// Key facts exploited:
//  - The scan is over t=256 (original batch axis); the n axis (96 positions)
//    NEVER mixes across layers (per-n einsum, per-n carry, per-n concat).
//    => one block owns one chain (both directions) for all 48 layers, with
//    __syncthreads() between phases. No inter-layer kernel launches, no HBM
//    round-trips for activations.
//  - x1 = h[:, -48:, :] => stack-1 chains n<48 are dead code. Only n in
//    [48,96) are computed (48 blocks total).
//
// Block: 512 threads (8 waves), LDS = xgF[256][64] + xgB[256][64] = 128 KB.
//  phase A (gates, layer M>=1): wave w owns t in [w*32,(w+1)*32). It reads
//    the compact h of both dirs from row positions [0..15] (broadcast b128),
//    then overwrites the full row with the new gates. Row touched by exactly
//    one wave; in-wave LDS ordering makes read-then-overwrite safe.
//  phase B (recurrence, layer L): wave 0 = fwd on xgF, wave 4 = bwd on xgB.
//    Same proven per-step macro as round-5, except h is written to
//    xg[t*64 + r] (r = g*16+j): 64 distinct addresses (conflict-free) and the
//    g==0 lanes land h[j] compactly at [0..15] for the next phase A.
//  Only x1 (after L=23) and h2 (after L=47) are written to global, in the
//    compact (t*48 + n)*32 layout consumed by fc1.
// ---------------------------------------------------------------------------

template <int SEL>
__device__ __forceinline__ float quad_bcast(float v) {
  return __int_as_float(__builtin_amdgcn_update_dpp(
      0, __float_as_int(v), SEL * 0x55, 0xF, 0xF, true));
}

__global__ __launch_bounds__(512) void lstm_fused(
    const float* __restrict__ x, const float* __restrict__ W_ih0_1,
    const float* __restrict__ W_ih_1, const float* __restrict__ W_hh_1,
    const float* __restrict__ b_ih_1, const float* __restrict__ b_hh_1,
    const float* __restrict__ W_ih_2, const float* __restrict__ W_hh_2,
    const float* __restrict__ b_ih_2, const float* __restrict__ b_hh_2,
    float* __restrict__ x1out, float* __restrict__ h2out) {
  __shared__ float xgF[256 * 64];  // 64 KB, fwd direction
  __shared__ float xgB[256 * 64];  // 64 KB, bwd direction

  const int tid = threadIdx.x;
  const int lane = tid & 63;
  const int w = tid >> 6;       // 0..7
  const int np = blockIdx.x;    // 0..47 (stack-2 chain index)
  const int nglob = 48 + np;    // stack-1 chain index (n<48 is dead code)

  // ---- layer 0 phase A (in_sz = 1): waves 0-3 fwd, 4-7 bwd ----
  {
    const int d = w >> 2;
    const int wv = w & 3;
    float* xg = d ? xgB : xgF;
    const int r = lane;
    const float bias = b_ih_1[d * 64 + r] + b_hh_1[d * 64 + r];
    const float wih0 = W_ih0_1[d * 64 + r];
    const int xvb =
        __float_as_int(x[(size_t)(wv * 64 + lane) * 96 + nglob]);
    for (int ti = 0; ti < 64; ++ti) {
      const float xs = __int_as_float(__builtin_amdgcn_readlane(xvb, ti));
      xg[(wv * 64 + ti) * 64 + r] = fmaf(wih0, xs, bias);
    }
  }
  __syncthreads();

  for (int L = 0; L < 48; ++L) {
    // ---- phase B: recurrence of layer L (wave 0 fwd, wave 4 bwd) ----
    if ((w & 3) == 0) {
      const int d = w >> 2;
      float* xg = d ? xgB : xgF;
      const int j = lane >> 2;
      const int g = lane & 3;
      const int r = g * 16 + j;

      const float* WhhP =
          ((L < 24) ? (W_hh_1 + (size_t)L * 2048)
                    : (W_hh_2 + (size_t)(L - 24) * 2048)) +
          (size_t)d * 1024 + (size_t)r * 16;
      float whh[16];
#pragma unroll
      for (int k = 0; k < 16; ++k) whh[k] = WhhP[k];

      // per-lane activation: sigmoid (g!=2) or tanh (g==2)
      const float s_ = (g == 2) ? 2.885390082f : -1.442695041f;
      const float m_ = (g == 2) ? -2.0f : 1.0f;
      const float b_ = (g == 2) ? 1.0f : 0.0f;

      float hs[16];
#pragma unroll
      for (int k = 0; k < 16; ++k) hs[k] = 0.f;
      float c = 0.f;

      const int dt = d ? -1 : 1;
      int t = d ? 255 : 0;
      float cur0 = xg[t * 64 + r];
      float cur1 = xg[(t + dt) * 64 + r];

#define LSTM_STEP(CUR, TT)                                                \
  {                                                                       \
    float a0 = (CUR), a1 = 0.f, a2 = 0.f, a3 = 0.f;                       \
    _Pragma("unroll") for (int k = 0; k < 16; k += 4) {                   \
      a0 = fmaf(whh[k + 0], hs[k + 0], a0);                               \
      a1 = fmaf(whh[k + 1], hs[k + 1], a1);                               \
      a2 = fmaf(whh[k + 2], hs[k + 2], a2);                               \
      a3 = fmaf(whh[k + 3], hs[k + 3], a3);                               \
    }                                                                     \
    const float gv = (a0 + a1) + (a2 + a3);                               \
    const float e = __builtin_amdgcn_exp2f(s_ * gv);                      \
    const float v = fmaf(m_, __builtin_amdgcn_rcpf(1.0f + e), b_);        \
    const float si = quad_bcast<0>(v);                                    \
    const float sf = quad_bcast<1>(v);                                    \
    const float tg = quad_bcast<2>(v);                                    \
    const float so = quad_bcast<3>(v);                                    \
    c = fmaf(sf, c, si * tg);                                             \
    const float e2 = __builtin_amdgcn_exp2f(2.885390082f * c);            \
    const float th = fmaf(-2.0f, __builtin_amdgcn_rcpf(1.0f + e2), 1.0f); \
    const float h = so * th;                                              \
    xg[(TT)*64 + r] = h; /* row consumed; g==0 lanes put h[j] at [0..15] */ \
    const int hb = __float_as_int(h);                                     \
    _Pragma("unroll") for (int k = 0; k < 16; ++k) hs[k] =                \
        __int_as_float(__builtin_amdgcn_readlane(hb, 4 * k));             \
  }

      for (int tt = 0; tt < 256; tt += 2) {
        const float nx0 = xg[((t + 2 * dt) & 255) * 64 + r];
        LSTM_STEP(cur0, t)
        const float nx1 = xg[((t + 3 * dt) & 255) * 64 + r];
        LSTM_STEP(cur1, t + dt)
        cur0 = nx0;
        cur1 = nx1;
        t += 2 * dt;
      }
#undef LSTM_STEP
    }
    __syncthreads();

    // ---- write-outs: x1 after stack 1, h2 at the end ----
    if (L == 23 || L == 47) {
      float* dst = (L == 23) ? x1out : h2out;
#pragma unroll
      for (int p = 0; p < 4; ++p) {
        const int gi = p * 512 + tid;  // 0..2047 float4 chunks
        const int t = gi >> 3;
        const int cc = gi & 7;  // chunk of 32 features: 0-3 fwd, 4-7 bwd
        const float* src = (cc < 4) ? &xgF[t * 64 + cc * 4]
                                    : &xgB[t * 64 + (cc - 4) * 4];
        const float4 v = *reinterpret_cast<const float4*>(src);
        *reinterpret_cast<float4*>(dst + ((size_t)t * 48 + np) * 32 +
                                   cc * 4) = v;
      }
      if (L == 47) break;
      __syncthreads();  // protect x1 reads from phase-A overwrite
    }

    // ---- phase A: gates of layer M = L+1 (all 8 waves, 32 rows each) ----
    {
      const int M = L + 1;
      const float* WihP;
      const float* bihP;
      const float* bhhP;
      if (M < 24) {
        WihP = W_ih_1 + (size_t)(M - 1) * 4096;  // (2,64,32) per layer
        bihP = b_ih_1 + (size_t)M * 128;
        bhhP = b_hh_1 + (size_t)M * 128;
      } else {
        WihP = W_ih_2 + (size_t)(M - 24) * 4096;
        bihP = b_ih_2 + (size_t)(M - 24) * 128;
        bhhP = b_hh_2 + (size_t)(M - 24) * 128;
      }
      const int r = lane;
      const float biasF = bihP[r] + bhhP[r];
      const float biasB = bihP[64 + r] + bhhP[64 + r];

      float wf[32], wb[32];
      {
        const float4* pf =
            reinterpret_cast<const float4*>(WihP + (size_t)r * 32);
        const float4* pb =
            reinterpret_cast<const float4*>(WihP + 2048 + (size_t)r * 32);
#pragma unroll
        for (int q = 0; q < 8; ++q) {
          const float4 a = pf[q];
          wf[4 * q + 0] = a.x;
          wf[4 * q + 1] = a.y;
          wf[4 * q + 2] = a.z;
          wf[4 * q + 3] = a.w;
          const float4 b = pb[q];
          wb[4 * q + 0] = b.x;
          wb[4 * q + 1] = b.y;
          wb[4 * q + 2] = b.z;
          wb[4 * q + 3] = b.w;
        }
      }

      for (int ti = 0; ti < 32; ++ti) {
        const int t = w * 32 + ti;
        const float4* qf = reinterpret_cast<const float4*>(&xgF[t * 64]);
        const float4* qb = reinterpret_cast<const float4*>(&xgB[t * 64]);
        float xv[32];
#pragma unroll
        for (int q = 0; q < 4; ++q) {
          const float4 a = qf[q];  // broadcast read of compact h_fwd
          xv[4 * q + 0] = a.x;
          xv[4 * q + 1] = a.y;
          xv[4 * q + 2] = a.z;
          xv[4 * q + 3] = a.w;
          const float4 b = qb[q];  // compact h_bwd
          xv[16 + 4 * q + 0] = b.x;
          xv[16 + 4 * q + 1] = b.y;
          xv[16 + 4 * q + 2] = b.z;
          xv[16 + 4 * q + 3] = b.w;
        }
        float f0 = biasF, f1 = 0.f, f2 = 0.f, f3 = 0.f;
        float g0 = biasB, g1 = 0.f, g2 = 0.f, g3 = 0.f;
#pragma unroll
        for (int k = 0; k < 32; k += 4) {
          f0 = fmaf(wf[k + 0], xv[k + 0], f0);
          f1 = fmaf(wf[k + 1], xv[k + 1], f1);
          f2 = fmaf(wf[k + 2], xv[k + 2], f2);
          f3 = fmaf(wf[k + 3], xv[k + 3], f3);
          g0 = fmaf(wb[k + 0], xv[k + 0], g0);
          g1 = fmaf(wb[k + 1], xv[k + 1], g1);
          g2 = fmaf(wb[k + 2], xv[k + 2], g2);
          g3 = fmaf(wb[k + 3], xv[k + 3], g3);
        }
        // reads of row t above precede these writes (in-wave LDS order);
        // no other wave touches row t.
        xgF[t * 64 + lane] = (f0 + f1) + (f2 + f3);
        xgB[t * 64 + lane] = (g0 + g1) + (g2 + g3);
      }
    }
    __syncthreads();
  }
}

// fc1: y1[b,m] = relu( sum_k (h2[b,k] + x1[b,k]) * w1[m,k] + b1[m] )
// Both h2 and x1 are now compact (256,1536).
__global__ __launch_bounds__(256) void fc1_kernel(
    const float* __restrict__ h2, const float* __restrict__ x1b,
    const float* __restrict__ w1, const float* __restrict__ b1,
    float* __restrict__ y1) {
  __shared__ float Zs[16][68];
  __shared__ float Ws[16][68];
  const int tid = threadIdx.x;
  const int m0 = blockIdx.x * 64;
  const int b0 = blockIdx.y * 64;
  const int rr = tid >> 2;
  const int c4 = (tid & 3) * 4;
  const int tx = tid & 15, ty = tid >> 4;

  float acc[4][4];
#pragma unroll
  for (int i = 0; i < 4; ++i)
#pragma unroll
    for (int jj = 0; jj < 4; ++jj) acc[i][jj] = 0.f;

  const bool wvalid = (m0 + rr) < 1000;
  const float* zr = h2 + (size_t)(b0 + rr) * 1536 + c4;
  const float* zr2 = x1b + (size_t)(b0 + rr) * 1536 + c4;
  const float* wr = w1 + (size_t)(m0 + rr) * 1536 + c4;

  float4 za = *reinterpret_cast<const float4*>(zr);
  float4 zb = *reinterpret_cast<const float4*>(zr2);
  float4 wv = wvalid ? *reinterpret_cast<const float4*>(wr)
                     : make_float4(0.f, 0.f, 0.f, 0.f);

  for (int k0 = 0; k0 < 1536; k0 += 16) {
    Zs[c4 + 0][rr] = za.x + zb.x;
    Zs[c4 + 1][rr] = za.y + zb.y;
    Zs[c4 + 2][rr] = za.z + zb.z;
    Zs[c4 + 3][rr] = za.w + zb.w;
    Ws[c4 + 0][rr] = wv.x;
    Ws[c4 + 1][rr] = wv.y;
    Ws[c4 + 2][rr] = wv.z;
    Ws[c4 + 3][rr] = wv.w;
    if (k0 + 16 < 1536) {
      za = *reinterpret_cast<const float4*>(zr + k0 + 16);
      zb = *reinterpret_cast<const float4*>(zr2 + k0 + 16);
      if (wvalid) wv = *reinterpret_cast<const float4*>(wr + k0 + 16);
    }
    __syncthreads();
#pragma unroll
    for (int kk = 0; kk < 16; ++kk) {
      const float4 av = *reinterpret_cast<const float4*>(&Zs[kk][ty * 4]);
      const float4 bv = *reinterpret_cast<const float4*>(&Ws[kk][tx * 4]);
      const float a_[4] = {av.x, av.y, av.z, av.w};
      const float b_[4] = {bv.x, bv.y, bv.z, bv.w};
#pragma unroll
      for (int i = 0; i < 4; ++i)
#pragma unroll
        for (int jj = 0; jj < 4; ++jj)
          acc[i][jj] = fmaf(a_[i], b_[jj], acc[i][jj]);
    }
    __syncthreads();
  }
#pragma unroll
  for (int i = 0; i < 4; ++i) {
    const int b = b0 + ty * 4 + i;
#pragma unroll
    for (int jj = 0; jj < 4; ++jj) {
      const int m = m0 + tx * 4 + jj;
      if (m < 1000) {
        float vo = acc[i][jj] + b1[m];
        y1[(size_t)b * 1000 + m] = vo > 0.f ? vo : 0.f;
      }
    }
  }
}

// fc2: out[b,p] = sum_m y1[b,m]*w2[p,m] + b2[p], p<48; FP32 store.
__global__ __launch_bounds__(64) void fc2_kernel(
    const float* __restrict__ y1, const float* __restrict__ w2,
    const float* __restrict__ b2, float* __restrict__ out) {
  __shared__ float ys[1000];
  const int b = blockIdx.x;
  for (int k = threadIdx.x; k < 1000; k += 64) ys[k] = y1[(size_t)b * 1000 + k];
  __syncthreads();
  const int p = threadIdx.x;
  if (p < 48) {
    float a0 = b2[p], a1 = 0.f, a2 = 0.f, a3 = 0.f;
    const float* wr = w2 + (size_t)p * 1000;
    for (int k = 0; k < 1000; k += 4) {
      const float4 wv = *reinterpret_cast<const float4*>(wr + k);
      a0 = fmaf(ys[k + 0], wv.x, a0);
      a1 = fmaf(ys[k + 1], wv.y, a1);
      a2 = fmaf(ys[k + 2], wv.z, a2);
      a3 = fmaf(ys[k + 3], wv.w, a3);
    }
    out[(size_t)b * 48 + p] = (a0 + a1) + (a2 + a3);
  }
}

extern "C" void kernel_launch(void* const* d_in, const int* in_sizes, int n_in,
                              void* d_out, int out_size, void* d_ws,
                              size_t ws_size, hipStream_t stream) {
  const float* x = (const float*)d_in[0];
  const float* W_ih0_1 = (const float*)d_in[1];
  const float* W_ih_1 = (const float*)d_in[2];
  const float* W_hh_1 = (const float*)d_in[3];
  const float* b_ih_1 = (const float*)d_in[4];
  const float* b_hh_1 = (const float*)d_in[5];
  const float* W_ih_2 = (const float*)d_in[6];
  const float* W_hh_2 = (const float*)d_in[7];
  const float* b_ih_2 = (const float*)d_in[8];
  const float* b_hh_2 = (const float*)d_in[9];
  const float* fc1_w = (const float*)d_in[10];
  const float* fc1_b = (const float*)d_in[11];
  const float* fc2_w = (const float*)d_in[12];
  const float* fc2_b = (const float*)d_in[13];

  float* ws = (float*)d_ws;
  float* x1b = ws;               // 393216 floats (256*48*32)
  float* h2b = ws + 393216;      // 393216 floats
  float* y1 = ws + 786432;       // 256000 floats

  lstm_fused<<<48, 512, 0, stream>>>(x, W_ih0_1, W_ih_1, W_hh_1, b_ih_1,
                                     b_hh_1, W_ih_2, W_hh_2, b_ih_2, b_hh_2,
                                     x1b, h2b);
  fc1_kernel<<<dim3(16, 4), 256, 0, stream>>>(h2b, x1b, fc1_w, fc1_b, y1);
  fc2_kernel<<<256, 64, 0, stream>>>(y1, fc2_w, fc2_b, (float*)d_out);
}

// Round 2
// 2494.973 us; speedup vs baseline: 1.2278x; 1.2278x over previous
//
#include <hip/hip_runtime.h>

// ---------------------------------------------------------------------------
// Round-7: fused 48-layer biLSTM (one kernel, 48 blocks, 8 waves), fixed for
// the round-6 regression:
//  - Phase B (serial recurrence) ran on waves 0 and 4 => BOTH on SIMD 0
//    (wave->SIMD is round-robin %4). Phase B is issue-bound (~70 VALU
//    inst/step), so the two chains halved each other's issue bandwidth.
//    Now: wave 0 = fwd (SIMD 0), wave 5 = bwd (SIMD 1).
//  - Phase-A weights (Wih rows + biases) are prefetched at loop top, BEFORE
//    phase B: raw loads only (no dependent arithmetic), so the waitcnt lands
//    at first use in phase A and the L2 latency hides under phase B.
//  - Phase A is 2-row software-pipelined (row t+1's 8 broadcast b128 LDS
//    reads issued during row t's 64 FMAs).
//
// Structure (unchanged from round-6):
//  - One block per live chain n in [48,96) (stack-1 chains n<48 are dead:
//    x1 = h[:, -48:, :] and the n axis never mixes across layers).
//  - LDS: xgF[256][64] + xgB[256][64] = 128 KB. Phase A writes gates, phase B
//    consumes them and overwrites each row with h (g==0 lanes land h[j]
//    compactly at row positions [0..15]).
//  - Only x1 (L=23) and h2 (L=47) go to global, compact (t*48+n)*32 layout.
// ---------------------------------------------------------------------------

template <int SEL>
__device__ __forceinline__ float quad_bcast(float v) {
  return __int_as_float(__builtin_amdgcn_update_dpp(
      0, __float_as_int(v), SEL * 0x55, 0xF, 0xF, true));
}

__global__ __launch_bounds__(512) void lstm_fused(
    const float* __restrict__ x, const float* __restrict__ W_ih0_1,
    const float* __restrict__ W_ih_1, const float* __restrict__ W_hh_1,
    const float* __restrict__ b_ih_1, const float* __restrict__ b_hh_1,
    const float* __restrict__ W_ih_2, const float* __restrict__ W_hh_2,
    const float* __restrict__ b_ih_2, const float* __restrict__ b_hh_2,
    float* __restrict__ x1out, float* __restrict__ h2out) {
  __shared__ float xgF[256 * 64];  // 64 KB, fwd direction
  __shared__ float xgB[256 * 64];  // 64 KB, bwd direction

  const int tid = threadIdx.x;
  const int lane = tid & 63;
  const int w = tid >> 6;     // 0..7
  const int np = blockIdx.x;  // 0..47 (stack-2 chain index)
  const int nglob = 48 + np;  // stack-1 chain index

  // ---- layer 0 phase A (in_sz = 1): waves 0-3 fwd, 4-7 bwd ----
  {
    const int d = w >> 2;
    const int wv = w & 3;
    float* xg = d ? xgB : xgF;
    const int r = lane;
    const float bias = b_ih_1[d * 64 + r] + b_hh_1[d * 64 + r];
    const float wih0 = W_ih0_1[d * 64 + r];
    const int xvb = __float_as_int(x[(size_t)(wv * 64 + lane) * 96 + nglob]);
    for (int ti = 0; ti < 64; ++ti) {
      const float xs = __int_as_float(__builtin_amdgcn_readlane(xvb, ti));
      xg[(wv * 64 + ti) * 64 + r] = fmaf(wih0, xs, bias);
    }
  }
  __syncthreads();

  for (int L = 0; L < 48; ++L) {
    // ---- prefetch phase-A weights for layer M=L+1 (clamped; the L==47
    // prefetch targets layer 23 of stack 2 — in-bounds, values unused). Raw
    // loads only: waitcnt is deferred to first use in phase A, so the load
    // latency hides under phase B. ----
    float wf[32], wb[32];
    float bf0, bf1, bb0, bb1;
    {
      const int M = (L < 47) ? (L + 1) : 47;
      const float* WihP;
      const float* bihP;
      const float* bhhP;
      if (M < 24) {
        WihP = W_ih_1 + (size_t)(M - 1) * 4096;  // (2,64,32) per layer
        bihP = b_ih_1 + (size_t)M * 128;
        bhhP = b_hh_1 + (size_t)M * 128;
      } else {
        WihP = W_ih_2 + (size_t)(M - 24) * 4096;
        bihP = b_ih_2 + (size_t)(M - 24) * 128;
        bhhP = b_hh_2 + (size_t)(M - 24) * 128;
      }
      const int r = lane;
      bf0 = bihP[r];
      bf1 = bhhP[r];
      bb0 = bihP[64 + r];
      bb1 = bhhP[64 + r];
      const float4* pf = reinterpret_cast<const float4*>(WihP + (size_t)r * 32);
      const float4* pb =
          reinterpret_cast<const float4*>(WihP + 2048 + (size_t)r * 32);
#pragma unroll
      for (int q = 0; q < 8; ++q) {
        const float4 a = pf[q];
        wf[4 * q + 0] = a.x;
        wf[4 * q + 1] = a.y;
        wf[4 * q + 2] = a.z;
        wf[4 * q + 3] = a.w;
        const float4 b = pb[q];
        wb[4 * q + 0] = b.x;
        wb[4 * q + 1] = b.y;
        wb[4 * q + 2] = b.z;
        wb[4 * q + 3] = b.w;
      }
    }

    // ---- phase B: recurrence of layer L. wave 0 = fwd (SIMD 0),
    //      wave 5 = bwd (SIMD 1) — different SIMDs, full issue BW each. ----
    if (w == 0 || w == 5) {
      const int d = (w == 5);
      float* xg = d ? xgB : xgF;
      const int j = lane >> 2;
      const int g = lane & 3;
      const int r = g * 16 + j;

      const float* WhhP = ((L < 24) ? (W_hh_1 + (size_t)L * 2048)
                                    : (W_hh_2 + (size_t)(L - 24) * 2048)) +
                          (size_t)d * 1024 + (size_t)r * 16;
      float whh[16];
#pragma unroll
      for (int k = 0; k < 16; ++k) whh[k] = WhhP[k];

      // per-lane activation: sigmoid (g!=2) or tanh (g==2)
      const float s_ = (g == 2) ? 2.885390082f : -1.442695041f;
      const float m_ = (g == 2) ? -2.0f : 1.0f;
      const float b_ = (g == 2) ? 1.0f : 0.0f;

      float hs[16];
#pragma unroll
      for (int k = 0; k < 16; ++k) hs[k] = 0.f;
      float c = 0.f;

      const int dt = d ? -1 : 1;
      int t = d ? 255 : 0;
      float cur0 = xg[t * 64 + r];
      float cur1 = xg[(t + dt) * 64 + r];

#define LSTM_STEP(CUR, TT)                                                  \
  {                                                                         \
    float a0 = (CUR), a1 = 0.f, a2 = 0.f, a3 = 0.f;                         \
    _Pragma("unroll") for (int k = 0; k < 16; k += 4) {                     \
      a0 = fmaf(whh[k + 0], hs[k + 0], a0);                                 \
      a1 = fmaf(whh[k + 1], hs[k + 1], a1);                                 \
      a2 = fmaf(whh[k + 2], hs[k + 2], a2);                                 \
      a3 = fmaf(whh[k + 3], hs[k + 3], a3);                                 \
    }                                                                       \
    const float gv = (a0 + a1) + (a2 + a3);                                 \
    const float e = __builtin_amdgcn_exp2f(s_ * gv);                        \
    const float v = fmaf(m_, __builtin_amdgcn_rcpf(1.0f + e), b_);          \
    const float si = quad_bcast<0>(v);                                      \
    const float sf = quad_bcast<1>(v);                                      \
    const float tg = quad_bcast<2>(v);                                      \
    const float so = quad_bcast<3>(v);                                      \
    c = fmaf(sf, c, si * tg);                                               \
    const float e2 = __builtin_amdgcn_exp2f(2.885390082f * c);              \
    const float th = fmaf(-2.0f, __builtin_amdgcn_rcpf(1.0f + e2), 1.0f);   \
    const float h = so * th;                                                \
    xg[(TT)*64 + r] = h; /* row consumed; g==0 lanes put h[j] at [0..15] */ \
    const int hb = __float_as_int(h);                                       \
    _Pragma("unroll") for (int k = 0; k < 16; ++k) hs[k] =                  \
        __int_as_float(__builtin_amdgcn_readlane(hb, 4 * k));               \
  }

      for (int tt = 0; tt < 256; tt += 2) {
        const float nx0 = xg[((t + 2 * dt) & 255) * 64 + r];
        LSTM_STEP(cur0, t)
        const float nx1 = xg[((t + 3 * dt) & 255) * 64 + r];
        LSTM_STEP(cur1, t + dt)
        cur0 = nx0;
        cur1 = nx1;
        t += 2 * dt;
      }
#undef LSTM_STEP
    }
    __syncthreads();

    // ---- write-outs: x1 after stack 1, h2 at the end ----
    if (L == 23 || L == 47) {
      float* dst = (L == 23) ? x1out : h2out;
#pragma unroll
      for (int p = 0; p < 4; ++p) {
        const int gi = p * 512 + tid;  // 0..2047 float4 chunks
        const int t = gi >> 3;
        const int cc = gi & 7;  // chunk of 32 features: 0-3 fwd, 4-7 bwd
        const float* src =
            (cc < 4) ? &xgF[t * 64 + cc * 4] : &xgB[t * 64 + (cc - 4) * 4];
        const float4 v = *reinterpret_cast<const float4*>(src);
        *reinterpret_cast<float4*>(dst + ((size_t)t * 48 + np) * 32 + cc * 4) =
            v;
      }
      if (L == 47) break;
      __syncthreads();  // protect x1 reads from phase-A overwrite
    }

    // ---- phase A: gates of layer M = L+1 (all 8 waves, 32 rows each),
    //      2-row software pipeline on the broadcast LDS reads. ----
    {
      const float biasF = bf0 + bf1;
      const float biasB = bb0 + bb1;

      float4 nf[4], nb[4];
      {
        const float4* qf = reinterpret_cast<const float4*>(&xgF[(w * 32) * 64]);
        const float4* qb = reinterpret_cast<const float4*>(&xgB[(w * 32) * 64]);
#pragma unroll
        for (int q = 0; q < 4; ++q) {
          nf[q] = qf[q];
          nb[q] = qb[q];
        }
      }
      for (int ti = 0; ti < 32; ++ti) {
        const int t = w * 32 + ti;
        float xv[32];
#pragma unroll
        for (int q = 0; q < 4; ++q) {
          const float4 a = nf[q];  // compact h_fwd of row t
          xv[4 * q + 0] = a.x;
          xv[4 * q + 1] = a.y;
          xv[4 * q + 2] = a.z;
          xv[4 * q + 3] = a.w;
          const float4 b = nb[q];  // compact h_bwd of row t
          xv[16 + 4 * q + 0] = b.x;
          xv[16 + 4 * q + 1] = b.y;
          xv[16 + 4 * q + 2] = b.z;
          xv[16 + 4 * q + 3] = b.w;
        }
        if (ti < 31) {  // prefetch row t+1 during the FMAs below
          const float4* qf =
              reinterpret_cast<const float4*>(&xgF[(t + 1) * 64]);
          const float4* qb =
              reinterpret_cast<const float4*>(&xgB[(t + 1) * 64]);
#pragma unroll
          for (int q = 0; q < 4; ++q) {
            nf[q] = qf[q];
            nb[q] = qb[q];
          }
        }
        float f0 = biasF, f1 = 0.f, f2 = 0.f, f3 = 0.f;
        float g0 = biasB, g1 = 0.f, g2 = 0.f, g3 = 0.f;
#pragma unroll
        for (int k = 0; k < 32; k += 4) {
          f0 = fmaf(wf[k + 0], xv[k + 0], f0);
          f1 = fmaf(wf[k + 1], xv[k + 1], f1);
          f2 = fmaf(wf[k + 2], xv[k + 2], f2);
          f3 = fmaf(wf[k + 3], xv[k + 3], f3);
          g0 = fmaf(wb[k + 0], xv[k + 0], g0);
          g1 = fmaf(wb[k + 1], xv[k + 1], g1);
          g2 = fmaf(wb[k + 2], xv[k + 2], g2);
          g3 = fmaf(wb[k + 3], xv[k + 3], g3);
        }
        // reads of row t (incl. its prefetch) precede these writes in-wave;
        // no other wave touches row t.
        xgF[t * 64 + lane] = (f0 + f1) + (f2 + f3);
        xgB[t * 64 + lane] = (g0 + g1) + (g2 + g3);
      }
    }
    __syncthreads();
  }
}

// fc1: y1[b,m] = relu( sum_k (h2[b,k] + x1[b,k]) * w1[m,k] + b1[m] )
// Both h2 and x1 are compact (256,1536).
__global__ __launch_bounds__(256) void fc1_kernel(
    const float* __restrict__ h2, const float* __restrict__ x1b,
    const float* __restrict__ w1, const float* __restrict__ b1,
    float* __restrict__ y1) {
  __shared__ float Zs[16][68];
  __shared__ float Ws[16][68];
  const int tid = threadIdx.x;
  const int m0 = blockIdx.x * 64;
  const int b0 = blockIdx.y * 64;
  const int rr = tid >> 2;
  const int c4 = (tid & 3) * 4;
  const int tx = tid & 15, ty = tid >> 4;

  float acc[4][4];
#pragma unroll
  for (int i = 0; i < 4; ++i)
#pragma unroll
    for (int jj = 0; jj < 4; ++jj) acc[i][jj] = 0.f;

  const bool wvalid = (m0 + rr) < 1000;
  const float* zr = h2 + (size_t)(b0 + rr) * 1536 + c4;
  const float* zr2 = x1b + (size_t)(b0 + rr) * 1536 + c4;
  const float* wr = w1 + (size_t)(m0 + rr) * 1536 + c4;

  float4 za = *reinterpret_cast<const float4*>(zr);
  float4 zb = *reinterpret_cast<const float4*>(zr2);
  float4 wv = wvalid ? *reinterpret_cast<const float4*>(wr)
                     : make_float4(0.f, 0.f, 0.f, 0.f);

  for (int k0 = 0; k0 < 1536; k0 += 16) {
    Zs[c4 + 0][rr] = za.x + zb.x;
    Zs[c4 + 1][rr] = za.y + zb.y;
    Zs[c4 + 2][rr] = za.z + zb.z;
    Zs[c4 + 3][rr] = za.w + zb.w;
    Ws[c4 + 0][rr] = wv.x;
    Ws[c4 + 1][rr] = wv.y;
    Ws[c4 + 2][rr] = wv.z;
    Ws[c4 + 3][rr] = wv.w;
    if (k0 + 16 < 1536) {
      za = *reinterpret_cast<const float4*>(zr + k0 + 16);
      zb = *reinterpret_cast<const float4*>(zr2 + k0 + 16);
      if (wvalid) wv = *reinterpret_cast<const float4*>(wr + k0 + 16);
    }
    __syncthreads();
#pragma unroll
    for (int kk = 0; kk < 16; ++kk) {
      const float4 av = *reinterpret_cast<const float4*>(&Zs[kk][ty * 4]);
      const float4 bv = *reinterpret_cast<const float4*>(&Ws[kk][tx * 4]);
      const float a_[4] = {av.x, av.y, av.z, av.w};
      const float b_[4] = {bv.x, bv.y, bv.z, bv.w};
#pragma unroll
      for (int i = 0; i < 4; ++i)
#pragma unroll
        for (int jj = 0; jj < 4; ++jj)
          acc[i][jj] = fmaf(a_[i], b_[jj], acc[i][jj]);
    }
    __syncthreads();
  }
#pragma unroll
  for (int i = 0; i < 4; ++i) {
    const int b = b0 + ty * 4 + i;
#pragma unroll
    for (int jj = 0; jj < 4; ++jj) {
      const int m = m0 + tx * 4 + jj;
      if (m < 1000) {
        float vo = acc[i][jj] + b1[m];
        y1[(size_t)b * 1000 + m] = vo > 0.f ? vo : 0.f;
      }
    }
  }
}

// fc2: out[b,p] = sum_m y1[b,m]*w2[p,m] + b2[p], p<48; FP32 store.
__global__ __launch_bounds__(64) void fc2_kernel(
    const float* __restrict__ y1, const float* __restrict__ w2,
    const float* __restrict__ b2, float* __restrict__ out) {
  __shared__ float ys[1000];
  const int b = blockIdx.x;
  for (int k = threadIdx.x; k < 1000; k += 64) ys[k] = y1[(size_t)b * 1000 + k];
  __syncthreads();
  const int p = threadIdx.x;
  if (p < 48) {
    float a0 = b2[p], a1 = 0.f, a2 = 0.f, a3 = 0.f;
    const float* wr = w2 + (size_t)p * 1000;
    for (int k = 0; k < 1000; k += 4) {
      const float4 wv = *reinterpret_cast<const float4*>(wr + k);
      a0 = fmaf(ys[k + 0], wv.x, a0);
      a1 = fmaf(ys[k + 1], wv.y, a1);
      a2 = fmaf(ys[k + 2], wv.z, a2);
      a3 = fmaf(ys[k + 3], wv.w, a3);
    }
    out[(size_t)b * 48 + p] = (a0 + a1) + (a2 + a3);
  }
}

extern "C" void kernel_launch(void* const* d_in, const int* in_sizes, int n_in,
                              void* d_out, int out_size, void* d_ws,
                              size_t ws_size, hipStream_t stream) {
  const float* x = (const float*)d_in[0];
  const float* W_ih0_1 = (const float*)d_in[1];
  const float* W_ih_1 = (const float*)d_in[2];
  const float* W_hh_1 = (const float*)d_in[3];
  const float* b_ih_1 = (const float*)d_in[4];
  const float* b_hh_1 = (const float*)d_in[5];
  const float* W_ih_2 = (const float*)d_in[6];
  const float* W_hh_2 = (const float*)d_in[7];
  const float* b_ih_2 = (const float*)d_in[8];
  const float* b_hh_2 = (const float*)d_in[9];
  const float* fc1_w = (const float*)d_in[10];
  const float* fc1_b = (const float*)d_in[11];
  const float* fc2_w = (const float*)d_in[12];
  const float* fc2_b = (const float*)d_in[13];

  float* ws = (float*)d_ws;
  float* x1b = ws;           // 393216 floats (256*48*32)
  float* h2b = ws + 393216;  // 393216 floats
  float* y1 = ws + 786432;   // 256000 floats

  lstm_fused<<<48, 512, 0, stream>>>(x, W_ih0_1, W_ih_1, W_hh_1, b_ih_1,
                                     b_hh_1, W_ih_2, W_hh_2, b_ih_2, b_hh_2,
                                     x1b, h2b);
  fc1_kernel<<<dim3(16, 4), 256, 0, stream>>>(h2b, x1b, fc1_w, fc1_b, y1);
  fc2_kernel<<<256, 64, 0, stream>>>(y1, fc2_w, fc2_b, (float*)d_out);
}